// Round 7
// baseline (174.746 us; speedup 1.0000x reference)
//
#include <hip/hip_runtime.h>
#include <stdint.h>

// ---------- constants ----------
#define T_WIN   4096
#define DFULL   4096
#define DK      1024
#define LOG2_10000 13.287712379549449f

// ---------- workspace layout (bytes), non-overlapping ----------
static const size_t IDX_OFF  = 0;         // idxb [4096][16] uchar   = 65536
static const size_t FRQ_OFF  = 65536;     // freqt [2048] f          = 8192
static const size_t KQ_OFF   = 73728;     // kq    [4096] f          = 16384
static const size_t S_OFF    = 90112;     // s     [4096] f          = 16384
// ---- contiguous zero region: 10496 floats = 41984 B ----
static const size_t QP_OFF   = 106496;    // qp   [4][1024] f
static const size_t AXPE_OFF = 122880;    // axpe [4096] f
static const size_t W_OFF    = 139264;    // weight [144] f (pad 256)
static const size_t CTX_OFF  = 140288;    // ctx [1024] f
static const size_t OL_OFF   = 144384;    // ol  [1024] f
// end 148480

// =====================================================================
// K1: blocks 0..255 idx extraction; block 256: zero atomic targets + freq
// =====================================================================
__global__ void setup_k(const int* __restrict__ obs,
                        unsigned char* __restrict__ idxb,
                        float* __restrict__ freqt,
                        float* __restrict__ zbase) {
    int b = blockIdx.x, tid = threadIdx.x;
    if (b < 256) {
        int g = b * 256 + tid;               // obs row = t*16 + pl*2 + which
        const int* r = obs + (size_t)g * 9;
        int id = 0;
        #pragma unroll
        for (int j = 1; j < 9; ++j) id += j * r[j];
        int t = g >> 4, pl = (g >> 1) & 7, which = g & 1;
        idxb[t * 16 + which * 8 + pl] = (unsigned char)id;
    } else {
        for (int i = tid; i < 10496; i += 256) zbase[i] = 0.0f;
        for (int i = tid; i < 2048; i += 256)
            freqt[i] = exp2f(-((float)(2 * i) * (1.0f / 4096.0f)) * LOG2_10000);
    }
}

// =====================================================================
// K2: q partials; block b = k-chunk of 16 rows, x derived from obs directly
// =====================================================================
__global__ void q_k(const int* __restrict__ obs,
                    const float* __restrict__ o_emb,
                    const float* __restrict__ d_emb,
                    const float* __restrict__ WQ,
                    float* __restrict__ qp) {
    __shared__ float lx[16];
    int b = blockIdx.x, tid = threadIdx.x;
    int kb = b * 16;
    int pl = kb >> 9, rr = kb & 511;
    const float* tab; int r0, which;
    if (rr < 256) { tab = o_emb; r0 = rr;       which = 0; }
    else          { tab = d_emb; r0 = rr - 256; which = 1; }
    if (tid < 16) {
        int row = 65520 + pl * 2 + which;     // t = 4095 rows
        const int* r = obs + (size_t)row * 9;
        int id = 0;
        #pragma unroll
        for (int j = 1; j < 9; ++j) id += j * r[j];
        int c = kb + tid;
        float f = exp2f(-((float)(c & ~1) * (1.0f / 4096.0f)) * LOG2_10000);
        float sv, cv;
        __sincosf(4095.0f * f, &sv, &cv);
        lx[tid] = tab[id * 256 + r0 + tid] * 16.0f + ((c & 1) ? cv : sv);
    }
    __syncthreads();
    const float4* W4 = (const float4*)WQ;
    float4 acc = {0.f, 0.f, 0.f, 0.f};
    #pragma unroll
    for (int k = 0; k < 16; ++k) {
        float xv = lx[k];
        float4 w = W4[(size_t)(kb + k) * 256 + tid];
        acc.x += xv * w.x; acc.y += xv * w.y;
        acc.z += xv * w.z; acc.w += xv * w.w;
    }
    float* dst = qp + (b >> 6) * 1024 + tid * 4;
    atomicAdd(dst + 0, acc.x);
    atomicAdd(dst + 1, acc.y);
    atomicAdd(dst + 2, acc.z);
    atomicAdd(dst + 3, acc.w);
}

// =====================================================================
// K3: kq[c] = (WK[c]·q)/32 ; q = sum of 4 partials. 4 rows per block.
// =====================================================================
__global__ void kq_k(const float* __restrict__ WK,
                     const float* __restrict__ qp,
                     float* __restrict__ kq) {
    __shared__ float4 qls[256];
    int tid = threadIdx.x;
    const float4* p4 = (const float4*)qp;
    float4 a = p4[tid], b4 = p4[256 + tid], c4 = p4[512 + tid], d4 = p4[768 + tid];
    qls[tid] = {a.x + b4.x + c4.x + d4.x, a.y + b4.y + c4.y + d4.y,
                a.z + b4.z + c4.z + d4.z, a.w + b4.w + c4.w + d4.w};
    __syncthreads();
    int wave = tid >> 6, lane = tid & 63;
    int cc = blockIdx.x * 4 + wave;
    const float4* W4 = (const float4*)(WK + (size_t)cc * DK);
    float acc = 0.0f;
    #pragma unroll
    for (int i = 0; i < 4; ++i) {
        float4 w = W4[i * 64 + lane];
        float4 q = qls[i * 64 + lane];
        acc += w.x * q.x + w.y * q.y + w.z * q.z + w.w * q.w;
    }
    #pragma unroll
    for (int off = 32; off; off >>= 1) acc += __shfl_down(acc, off, 64);
    if (lane == 0) kq[cc] = acc * (1.0f / 32.0f);
}

// =====================================================================
// K4: s[t] = sum_seg Dot[seg][idx] + pedot[t]  (R4-proven form, in-loop sincos)
// =====================================================================
__global__ __launch_bounds__(256) void scores_k(
        const float* __restrict__ kq,
        const float* __restrict__ o_emb, const float* __restrict__ d_emb,
        const float* __restrict__ freqt,
        const unsigned char* __restrict__ idxb,
        float* __restrict__ s) {
    __shared__ __align__(16) float lkq[4096];
    __shared__ float lemb[18 * 257];
    __shared__ __align__(16) float lfrq[2048];
    __shared__ float ldot[144];
    __shared__ float lped[256];
    int tid = threadIdx.x, b = blockIdx.x;
    for (int i = tid; i < 1024; i += 256)
        ((float4*)lkq)[i] = ((const float4*)kq)[i];
    for (int i = tid; i < 512; i += 256)
        ((float4*)lfrq)[i] = ((const float4*)freqt)[i];
    for (int i = tid; i < 4608; i += 256) {
        int row = i >> 8, r = i & 255;
        lemb[row * 257 + r] = (row < 9) ? o_emb[row * 256 + r]
                                        : d_emb[(row - 9) * 256 + r];
    }
    __syncthreads();
    if (tid < 144) {
        int seg = tid / 9, id = tid % 9;
        int base = (seg < 8) ? seg * 512 : (seg - 8) * 512 + 256;
        const float* e = lemb + ((seg < 8) ? id : (9 + id)) * 257;
        float a = 0.0f;
        for (int rr = 0; rr < 256; ++rr) {
            int r = (rr + seg * 4) & 255;
            a += e[r] * lkq[base + r];
        }
        ldot[tid] = 16.0f * a;
    }
    int tt = tid >> 4, sub = tid & 15;
    int t = b * 16 + tt;
    float acc = 0.0f;
    for (int jj = 0; jj < 128; ++jj) {
        int j = sub * 128 + ((jj + 2 * sub) & 127);
        float f = lfrq[j];
        float sv, cv;
        __sincosf((float)t * f, &sv, &cv);
        acc += sv * lkq[2 * j] + cv * lkq[2 * j + 1];
    }
    lped[tt * 16 + sub] = acc;
    __syncthreads();
    if (tid < 16) {
        int t2 = b * 16 + tid;
        float tot = 0.0f;
        #pragma unroll
        for (int i = 0; i < 16; ++i) tot += lped[tid * 16 + i];
        const uint32_t* ip = (const uint32_t*)(idxb + t2 * 16);
        uint32_t u0 = ip[0], u1 = ip[1], u2 = ip[2], u3 = ip[3];
        #pragma unroll
        for (int seg = 0; seg < 16; ++seg) {
            uint32_t u = (seg < 4) ? u0 : (seg < 8) ? u1 : (seg < 12) ? u2 : u3;
            int id = (u >> ((seg & 3) * 8)) & 0xFF;
            tot += ldot[seg * 9 + id];
        }
        s[t2] = tot;
    }
}

// =====================================================================
// K5: fused softmax + hist(weight) + axpe  (R6-validated). grid 128.
// =====================================================================
__global__ void att_post_k(const float* __restrict__ s,
                           const float* __restrict__ freqt,
                           const unsigned char* __restrict__ idxb,
                           float* __restrict__ weight,
                           float* __restrict__ axpe) {
    __shared__ __align__(16) float ls[4096];
    __shared__ float att_l[256];
    __shared__ float lh[144];
    __shared__ float red[4];
    __shared__ float bc[2];
    int tid = threadIdx.x, b = blockIdx.x;
    int wave = tid >> 6, lane = tid & 63;
    int C = b >> 3;
    #pragma unroll
    for (int k = 0; k < 4; ++k)
        ((float4*)ls)[tid + 256 * k] = ((const float4*)s)[tid + 256 * k];
    if (tid < 144) lh[tid] = 0.0f;
    __syncthreads();
    float lm = -1e30f;
    #pragma unroll
    for (int k = 0; k < 16; ++k) lm = fmaxf(lm, ls[tid + 256 * k]);
    #pragma unroll
    for (int off = 32; off; off >>= 1) lm = fmaxf(lm, __shfl_down(lm, off, 64));
    if (lane == 0) red[wave] = lm;
    __syncthreads();
    if (tid == 0) bc[0] = fmaxf(fmaxf(red[0], red[1]), fmaxf(red[2], red[3]));
    __syncthreads();
    float m = bc[0];
    float lsum = 0.0f;
    #pragma unroll
    for (int k = 0; k < 16; ++k) lsum += expf(ls[tid + 256 * k] - m);
    #pragma unroll
    for (int off = 32; off; off >>= 1) lsum += __shfl_down(lsum, off, 64);
    if (lane == 0) red[wave] = lsum;
    __syncthreads();
    if (tid == 0) bc[1] = 1.0f / (red[0] + red[1] + red[2] + red[3]);
    __syncthreads();
    float inv = bc[1];
    att_l[tid] = expf(ls[C * 256 + tid] - m) * inv;
    // hist: 32 t x 16 seg
    #pragma unroll
    for (int i = 0; i < 2; ++i) {
        int it = tid + 256 * i;
        int tl = it >> 4, seg = it & 15;
        int t = b * 32 + tl;
        float av = expf(ls[t] - m) * inv;
        atomicAdd(&lh[seg * 9 + idxb[t * 16 + seg]], av);
    }
    __syncthreads();
    if (tid < 144) atomicAdd(&weight[tid], lh[tid]);
    // axpe: one freq pair per thread over this 256-t chunk
    {
        int j = (b & 7) * 256 + tid;
        float f = freqt[j];
        float sf, cf;
        __sincosf(f, &sf, &cf);
        int t0 = C << 8;
        float ss = 0.f, sc = 0.f, sv = 0.f, cv = 0.f;
        for (int i = 0; i < 256; ++i) {
            if ((i & 63) == 0) __sincosf((float)(t0 + i) * f, &sv, &cv);
            float a = att_l[i];
            ss += a * sv; sc += a * cv;
            float ns = sv * cf + cv * sf;
            cv = cv * cf - sv * sf;
            sv = ns;
        }
        atomicAdd(&axpe[2 * j], ss);
        atomicAdd(&axpe[2 * j + 1], sc);
    }
}

// =====================================================================
// K6: ctx[n] += sum_{c in 32-row chunk} ax[c]*WV[c][n], float4 over n.
// grid 128 = cc(0..31) x rs(0..3); block rows c = cc*128+rs*32 .. +32
// =====================================================================
__global__ void ctxv_k(const float* __restrict__ weight,
                       const float* __restrict__ axpe,
                       const float* __restrict__ o_emb,
                       const float* __restrict__ d_emb,
                       const float* __restrict__ WV,
                       float* __restrict__ ctx) {
    __shared__ float lax[32];
    int tid = threadIdx.x;
    int cc = blockIdx.x >> 2, rs = blockIdx.x & 3;
    int c0 = cc * 128 + rs * 32;
    if (tid < 32) {
        int c = c0 + tid;
        int pl = c >> 9, rr = c & 511;
        int seg, r; const float* tab;
        if (rr < 256) { seg = pl;     r = rr;       tab = o_emb; }
        else          { seg = 8 + pl; r = rr - 256; tab = d_emb; }
        float a = 0.0f;
        #pragma unroll
        for (int id = 0; id < 9; ++id)
            a += weight[seg * 9 + id] * tab[id * 256 + r];
        lax[tid] = axpe[c] + 16.0f * a;
    }
    __syncthreads();
    const float4* W4 = (const float4*)WV;
    float4 acc = {0.f, 0.f, 0.f, 0.f};
    #pragma unroll 8
    for (int i = 0; i < 32; ++i) {
        float av = lax[i];
        float4 w = W4[(size_t)(c0 + i) * 256 + tid];
        acc.x += av * w.x; acc.y += av * w.y;
        acc.z += av * w.z; acc.w += av * w.w;
    }
    float* dst = ctx + tid * 4;
    atomicAdd(dst + 0, acc.x);
    atomicAdd(dst + 1, acc.y);
    atomicAdd(dst + 2, acc.z);
    atomicAdd(dst + 3, acc.w);
}

// =====================================================================
// K7: ol[m] += sum_{j in 16-row chunk} ctx[j]*WO[j][m], float4 over m.
// grid 64 = jc(0..15) x rs(0..3); rows j = jc*64+rs*16 .. +16
// =====================================================================
__global__ void olast_k(const float* __restrict__ ctx,
                        const float* __restrict__ WO,
                        float* __restrict__ ol) {
    __shared__ float lc[16];
    int tid = threadIdx.x;
    int jc = blockIdx.x >> 2, rs = blockIdx.x & 3;
    int j0 = jc * 64 + rs * 16;
    if (tid < 16) lc[tid] = ctx[j0 + tid];
    __syncthreads();
    const float4* W4 = (const float4*)WO;
    float4 acc = {0.f, 0.f, 0.f, 0.f};
    #pragma unroll
    for (int j = 0; j < 16; ++j) {
        float cv = lc[j];
        float4 w = W4[(size_t)(j0 + j) * 256 + tid];
        acc.x += cv * w.x; acc.y += cv * w.y;
        acc.z += cv * w.z; acc.w += cv * w.w;
    }
    float* dst = ol + tid * 4;
    atomicAdd(dst + 0, acc.x);
    atomicAdd(dst + 1, acc.y);
    atomicAdd(dst + 2, acc.z);
    atomicAdd(dst + 3, acc.w);
}

// =====================================================================
// K8: heads — float4 loads, one block per output
// =====================================================================
__global__ void heads_k(const float* __restrict__ ol,
                        const float* __restrict__ Wo_pol, const float* __restrict__ bo_pol,
                        const float* __restrict__ Wd_pol, const float* __restrict__ bd_pol,
                        const float* __restrict__ Wv,     const float* __restrict__ bv,
                        float* __restrict__ out) {
    __shared__ float red[4];
    int o = blockIdx.x, tid = threadIdx.x;
    const float* W; float b;
    if (o < 64)       { W = Wo_pol + (size_t)o * DK;        b = bo_pol[o]; }
    else if (o < 128) { W = Wd_pol + (size_t)(o - 64) * DK; b = bd_pol[o - 64]; }
    else              { W = Wv;                              b = bv[0]; }
    float4 h = ((const float4*)ol)[tid];
    float4 w = ((const float4*)W)[tid];
    float s = fmaxf(h.x, 0.f) * w.x + fmaxf(h.y, 0.f) * w.y
            + fmaxf(h.z, 0.f) * w.z + fmaxf(h.w, 0.f) * w.w;
    #pragma unroll
    for (int off = 32; off; off >>= 1) s += __shfl_down(s, off, 64);
    int wave = tid >> 6, lane = tid & 63;
    if (lane == 0) red[wave] = s;
    __syncthreads();
    if (tid == 0) out[o] = red[0] + red[1] + red[2] + red[3] + b;
}

// =====================================================================
extern "C" void kernel_launch(void* const* d_in, const int* in_sizes, int n_in,
                              void* d_out, int out_size, void* d_ws, size_t ws_size,
                              hipStream_t stream) {
    const int*   obs    = (const int*)  d_in[0];
    const float* o_emb  = (const float*)d_in[1];
    const float* d_emb  = (const float*)d_in[2];
    const float* WQ     = (const float*)d_in[3];
    const float* WK     = (const float*)d_in[4];
    const float* WV     = (const float*)d_in[5];
    const float* WO     = (const float*)d_in[6];
    const float* Wo_pol = (const float*)d_in[7];
    const float* bo_pol = (const float*)d_in[8];
    const float* Wd_pol = (const float*)d_in[9];
    const float* bd_pol = (const float*)d_in[10];
    const float* Wv     = (const float*)d_in[11];
    const float* bv     = (const float*)d_in[12];
    float* out = (float*)d_out;

    char* ws = (char*)d_ws;
    unsigned char* idxb = (unsigned char*)(ws + IDX_OFF);
    float* freqt = (float*)(ws + FRQ_OFF);
    float* kq    = (float*)(ws + KQ_OFF);
    float* s     = (float*)(ws + S_OFF);
    float* qp    = (float*)(ws + QP_OFF);
    float* axpe  = (float*)(ws + AXPE_OFF);
    float* wgt   = (float*)(ws + W_OFF);
    float* ctx   = (float*)(ws + CTX_OFF);
    float* ol    = (float*)(ws + OL_OFF);

    setup_k<<<257, 256, 0, stream>>>(obs, idxb, freqt, qp);
    q_k<<<256, 256, 0, stream>>>(obs, o_emb, d_emb, WQ, qp);
    kq_k<<<1024, 256, 0, stream>>>(WK, qp, kq);
    scores_k<<<256, 256, 0, stream>>>(kq, o_emb, d_emb, freqt, idxb, s);
    att_post_k<<<128, 256, 0, stream>>>(s, freqt, idxb, wgt, axpe);
    ctxv_k<<<128, 256, 0, stream>>>(wgt, axpe, o_emb, d_emb, WV, ctx);
    olast_k<<<64, 256, 0, stream>>>(ctx, WO, ol);
    heads_k<<<129, 256, 0, stream>>>(ol, Wo_pol, bo_pol, Wd_pol, bd_pol, Wv, bv, out);
}

// Round 8
// 173.131 us; speedup vs baseline: 1.0093x; 1.0093x over previous
//
#include <hip/hip_runtime.h>
#include <stdint.h>

// ---------- constants ----------
#define T_WIN   4096
#define DFULL   4096
#define DK      1024
#define LOG2_10000 13.287712379549449f

// ---------- workspace layout (bytes), non-overlapping ----------
static const size_t IDX_OFF  = 0;         // idxb [4096][16] uchar   = 65536
static const size_t FRQ_OFF  = 65536;     // freqt [2048] f          = 8192
static const size_t KQ_OFF   = 73728;     // kq    [4096] f          = 16384
static const size_t S_OFF    = 90112;     // s     [4096] f          = 16384
// ---- contiguous zero region: 10496 floats = 41984 B ----
static const size_t QP_OFF   = 106496;    // qp   [4][1024] f
static const size_t AXPE_OFF = 122880;    // axpe [4096] f
static const size_t W_OFF    = 139264;    // weight [144] f (pad 256)
static const size_t CTX_OFF  = 140288;    // ctx [1024] f
static const size_t OL_OFF   = 144384;    // ol  [1024] f
// end 148480

// =====================================================================
// K1: blocks 0..255 idx extraction; block 256: zero atomic targets + freq
// =====================================================================
__global__ void setup_k(const int* __restrict__ obs,
                        unsigned char* __restrict__ idxb,
                        float* __restrict__ freqt,
                        float* __restrict__ zbase) {
    int b = blockIdx.x, tid = threadIdx.x;
    if (b < 256) {
        int g = b * 256 + tid;               // obs row = t*16 + pl*2 + which
        const int* r = obs + (size_t)g * 9;
        int id = 0;
        #pragma unroll
        for (int j = 1; j < 9; ++j) id += j * r[j];
        int t = g >> 4, pl = (g >> 1) & 7, which = g & 1;
        idxb[t * 16 + which * 8 + pl] = (unsigned char)id;
    } else {
        for (int i = tid; i < 10496; i += 256) zbase[i] = 0.0f;
        for (int i = tid; i < 2048; i += 256)
            freqt[i] = exp2f(-((float)(2 * i) * (1.0f / 4096.0f)) * LOG2_10000);
    }
}

// =====================================================================
// K2: q partials; block b = k-chunk of 16 rows, x derived from obs directly
// =====================================================================
__global__ void q_k(const int* __restrict__ obs,
                    const float* __restrict__ o_emb,
                    const float* __restrict__ d_emb,
                    const float* __restrict__ WQ,
                    float* __restrict__ qp) {
    __shared__ float lx[16];
    int b = blockIdx.x, tid = threadIdx.x;
    int kb = b * 16;
    int pl = kb >> 9, rr = kb & 511;
    const float* tab; int r0, which;
    if (rr < 256) { tab = o_emb; r0 = rr;       which = 0; }
    else          { tab = d_emb; r0 = rr - 256; which = 1; }
    if (tid < 16) {
        int row = 65520 + pl * 2 + which;     // t = 4095 rows
        const int* r = obs + (size_t)row * 9;
        int id = 0;
        #pragma unroll
        for (int j = 1; j < 9; ++j) id += j * r[j];
        int c = kb + tid;
        float f = exp2f(-((float)(c & ~1) * (1.0f / 4096.0f)) * LOG2_10000);
        float sv, cv;
        __sincosf(4095.0f * f, &sv, &cv);
        lx[tid] = tab[id * 256 + r0 + tid] * 16.0f + ((c & 1) ? cv : sv);
    }
    __syncthreads();
    const float4* W4 = (const float4*)WQ;
    float4 acc = {0.f, 0.f, 0.f, 0.f};
    #pragma unroll
    for (int k = 0; k < 16; ++k) {
        float xv = lx[k];
        float4 w = W4[(size_t)(kb + k) * 256 + tid];
        acc.x += xv * w.x; acc.y += xv * w.y;
        acc.z += xv * w.z; acc.w += xv * w.w;
    }
    float* dst = qp + (b >> 6) * 1024 + tid * 4;
    atomicAdd(dst + 0, acc.x);
    atomicAdd(dst + 1, acc.y);
    atomicAdd(dst + 2, acc.z);
    atomicAdd(dst + 3, acc.w);
}

// =====================================================================
// K3: kq[c] = (WK[c]·q)/32 ; q = sum of 4 partials. 4 rows per block.
// =====================================================================
__global__ void kq_k(const float* __restrict__ WK,
                     const float* __restrict__ qp,
                     float* __restrict__ kq) {
    __shared__ float4 qls[256];
    int tid = threadIdx.x;
    const float4* p4 = (const float4*)qp;
    float4 a = p4[tid], b4 = p4[256 + tid], c4 = p4[512 + tid], d4 = p4[768 + tid];
    qls[tid] = {a.x + b4.x + c4.x + d4.x, a.y + b4.y + c4.y + d4.y,
                a.z + b4.z + c4.z + d4.z, a.w + b4.w + c4.w + d4.w};
    __syncthreads();
    int wave = tid >> 6, lane = tid & 63;
    int cc = blockIdx.x * 4 + wave;
    const float4* W4 = (const float4*)(WK + (size_t)cc * DK);
    float acc = 0.0f;
    #pragma unroll
    for (int i = 0; i < 4; ++i) {
        float4 w = W4[i * 64 + lane];
        float4 q = qls[i * 64 + lane];
        acc += w.x * q.x + w.y * q.y + w.z * q.z + w.w * q.w;
    }
    #pragma unroll
    for (int off = 32; off; off >>= 1) acc += __shfl_down(acc, off, 64);
    if (lane == 0) kq[cc] = acc * (1.0f / 32.0f);
}

// =====================================================================
// K4: s[t] = sum_seg Dot[seg][idx] + pedot[t]; float2 kq-pair LDS reads
// =====================================================================
__global__ __launch_bounds__(256) void scores_k(
        const float* __restrict__ kq,
        const float* __restrict__ o_emb, const float* __restrict__ d_emb,
        const float* __restrict__ freqt,
        const unsigned char* __restrict__ idxb,
        float* __restrict__ s) {
    __shared__ __align__(16) float lkq[4096];
    __shared__ float lemb[18 * 257];
    __shared__ __align__(16) float lfrq[2048];
    __shared__ float ldot[144];
    __shared__ float lped[256];
    int tid = threadIdx.x, b = blockIdx.x;
    for (int i = tid; i < 1024; i += 256)
        ((float4*)lkq)[i] = ((const float4*)kq)[i];
    for (int i = tid; i < 512; i += 256)
        ((float4*)lfrq)[i] = ((const float4*)freqt)[i];
    for (int i = tid; i < 4608; i += 256) {
        int row = i >> 8, r = i & 255;
        lemb[row * 257 + r] = (row < 9) ? o_emb[row * 256 + r]
                                        : d_emb[(row - 9) * 256 + r];
    }
    __syncthreads();
    if (tid < 144) {
        int seg = tid / 9, id = tid % 9;
        int base = (seg < 8) ? seg * 512 : (seg - 8) * 512 + 256;
        const float* e = lemb + ((seg < 8) ? id : (9 + id)) * 257;
        float a = 0.0f;
        for (int rr = 0; rr < 256; ++rr) {
            int r = (rr + seg * 4) & 255;
            a += e[r] * lkq[base + r];
        }
        ldot[tid] = 16.0f * a;
    }
    int tt = tid >> 4, sub = tid & 15;
    int t = b * 16 + tt;
    float acc = 0.0f;
    for (int jj = 0; jj < 128; ++jj) {
        int j = sub * 128 + ((jj + 2 * sub) & 127);
        float f = lfrq[j];
        float sv, cv;
        __sincosf((float)t * f, &sv, &cv);
        float2 kp = *(const float2*)(lkq + 2 * j);   // one ds_read_b64
        acc += sv * kp.x + cv * kp.y;
    }
    lped[tt * 16 + sub] = acc;
    __syncthreads();
    if (tid < 16) {
        int t2 = b * 16 + tid;
        float tot = 0.0f;
        #pragma unroll
        for (int i = 0; i < 16; ++i) tot += lped[tid * 16 + i];
        const uint32_t* ip = (const uint32_t*)(idxb + t2 * 16);
        uint32_t u0 = ip[0], u1 = ip[1], u2 = ip[2], u3 = ip[3];
        #pragma unroll
        for (int seg = 0; seg < 16; ++seg) {
            uint32_t u = (seg < 4) ? u0 : (seg < 8) ? u1 : (seg < 12) ? u2 : u3;
            int id = (u >> ((seg & 3) * 8)) & 0xFF;
            tot += ldot[seg * 9 + id];
        }
        s[t2] = tot;
    }
}

// =====================================================================
// K5: fused softmax + hist(weight) + axpe. grid 256 (full chip).
// hist: t in [b*16, b*16+16). axpe: window W=b>>3 (128 t), j=(b&7)*256+tid
// =====================================================================
__global__ void att_post_k(const float* __restrict__ s,
                           const float* __restrict__ freqt,
                           const unsigned char* __restrict__ idxb,
                           float* __restrict__ weight,
                           float* __restrict__ axpe) {
    __shared__ __align__(16) float ls[4096];
    __shared__ __align__(16) float att_l[128];
    __shared__ float lh[144];
    __shared__ float red[4];
    __shared__ float bc[2];
    int tid = threadIdx.x, b = blockIdx.x;
    int wave = tid >> 6, lane = tid & 63;
    int W = b >> 3;                       // t-window 0..31 (128 t each)
    #pragma unroll
    for (int k = 0; k < 4; ++k)
        ((float4*)ls)[tid + 256 * k] = ((const float4*)s)[tid + 256 * k];
    if (tid < 144) lh[tid] = 0.0f;
    __syncthreads();
    float lm = -1e30f;
    #pragma unroll
    for (int k = 0; k < 16; ++k) lm = fmaxf(lm, ls[tid + 256 * k]);
    #pragma unroll
    for (int off = 32; off; off >>= 1) lm = fmaxf(lm, __shfl_down(lm, off, 64));
    if (lane == 0) red[wave] = lm;
    __syncthreads();
    if (tid == 0) bc[0] = fmaxf(fmaxf(red[0], red[1]), fmaxf(red[2], red[3]));
    __syncthreads();
    float m = bc[0];
    float lsum = 0.0f;
    #pragma unroll
    for (int k = 0; k < 16; ++k) lsum += expf(ls[tid + 256 * k] - m);
    #pragma unroll
    for (int off = 32; off; off >>= 1) lsum += __shfl_down(lsum, off, 64);
    if (lane == 0) red[wave] = lsum;
    __syncthreads();
    if (tid == 0) bc[1] = 1.0f / (red[0] + red[1] + red[2] + red[3]);
    __syncthreads();
    float inv = bc[1];
    if (tid < 128) att_l[tid] = expf(ls[W * 128 + tid] - m) * inv;
    // hist: 16 t x 16 seg, t in [b*16, b*16+16)
    {
        int tl = tid >> 4, seg = tid & 15;
        int t = b * 16 + tl;
        float av = expf(ls[t] - m) * inv;
        atomicAdd(&lh[seg * 9 + idxb[t * 16 + seg]], av);
    }
    __syncthreads();
    if (tid < 144) atomicAdd(&weight[tid], lh[tid]);
    // axpe: one freq pair per thread over this 128-t window,
    // anchored rotation; att read as lane-uniform float4 broadcasts
    {
        int j = (b & 7) * 256 + tid;
        float f = freqt[j];
        float sf, cf;
        __sincosf(f, &sf, &cf);
        int t0 = W << 7;
        float ss = 0.f, sc = 0.f, sv = 0.f, cv = 0.f;
        for (int i = 0; i < 128; i += 4) {
            if ((i & 63) == 0) __sincosf((float)(t0 + i) * f, &sv, &cv);
            float4 a4 = *(const float4*)(att_l + i);   // ds_read_b128 broadcast
            float ns;
            ss += a4.x * sv; sc += a4.x * cv;
            ns = sv * cf + cv * sf; cv = cv * cf - sv * sf; sv = ns;
            ss += a4.y * sv; sc += a4.y * cv;
            ns = sv * cf + cv * sf; cv = cv * cf - sv * sf; sv = ns;
            ss += a4.z * sv; sc += a4.z * cv;
            ns = sv * cf + cv * sf; cv = cv * cf - sv * sf; sv = ns;
            ss += a4.w * sv; sc += a4.w * cv;
            ns = sv * cf + cv * sf; cv = cv * cf - sv * sf; sv = ns;
        }
        atomicAdd(&axpe[2 * j], ss);
        atomicAdd(&axpe[2 * j + 1], sc);
    }
}

// =====================================================================
// K6: ctx[n] += sum_{c in 32-row chunk} ax[c]*WV[c][n], float4 over n.
// =====================================================================
__global__ void ctxv_k(const float* __restrict__ weight,
                       const float* __restrict__ axpe,
                       const float* __restrict__ o_emb,
                       const float* __restrict__ d_emb,
                       const float* __restrict__ WV,
                       float* __restrict__ ctx) {
    __shared__ float lax[32];
    int tid = threadIdx.x;
    int cc = blockIdx.x >> 2, rs = blockIdx.x & 3;
    int c0 = cc * 128 + rs * 32;
    if (tid < 32) {
        int c = c0 + tid;
        int pl = c >> 9, rr = c & 511;
        int seg, r; const float* tab;
        if (rr < 256) { seg = pl;     r = rr;       tab = o_emb; }
        else          { seg = 8 + pl; r = rr - 256; tab = d_emb; }
        float a = 0.0f;
        #pragma unroll
        for (int id = 0; id < 9; ++id)
            a += weight[seg * 9 + id] * tab[id * 256 + r];
        lax[tid] = axpe[c] + 16.0f * a;
    }
    __syncthreads();
    const float4* W4 = (const float4*)WV;
    float4 acc = {0.f, 0.f, 0.f, 0.f};
    #pragma unroll 8
    for (int i = 0; i < 32; ++i) {
        float av = lax[i];
        float4 w = W4[(size_t)(c0 + i) * 256 + tid];
        acc.x += av * w.x; acc.y += av * w.y;
        acc.z += av * w.z; acc.w += av * w.w;
    }
    float* dst = ctx + tid * 4;
    atomicAdd(dst + 0, acc.x);
    atomicAdd(dst + 1, acc.y);
    atomicAdd(dst + 2, acc.z);
    atomicAdd(dst + 3, acc.w);
}

// =====================================================================
// K7: ol[m] += sum_{j in 16-row chunk} ctx[j]*WO[j][m], float4 over m.
// =====================================================================
__global__ void olast_k(const float* __restrict__ ctx,
                        const float* __restrict__ WO,
                        float* __restrict__ ol) {
    __shared__ float lc[16];
    int tid = threadIdx.x;
    int jc = blockIdx.x >> 2, rs = blockIdx.x & 3;
    int j0 = jc * 64 + rs * 16;
    if (tid < 16) lc[tid] = ctx[j0 + tid];
    __syncthreads();
    const float4* W4 = (const float4*)WO;
    float4 acc = {0.f, 0.f, 0.f, 0.f};
    #pragma unroll
    for (int j = 0; j < 16; ++j) {
        float cv = lc[j];
        float4 w = W4[(size_t)(j0 + j) * 256 + tid];
        acc.x += cv * w.x; acc.y += cv * w.y;
        acc.z += cv * w.z; acc.w += cv * w.w;
    }
    float* dst = ol + tid * 4;
    atomicAdd(dst + 0, acc.x);
    atomicAdd(dst + 1, acc.y);
    atomicAdd(dst + 2, acc.z);
    atomicAdd(dst + 3, acc.w);
}

// =====================================================================
// K8: heads — float4 loads, one block per output
// =====================================================================
__global__ void heads_k(const float* __restrict__ ol,
                        const float* __restrict__ Wo_pol, const float* __restrict__ bo_pol,
                        const float* __restrict__ Wd_pol, const float* __restrict__ bd_pol,
                        const float* __restrict__ Wv,     const float* __restrict__ bv,
                        float* __restrict__ out) {
    __shared__ float red[4];
    int o = blockIdx.x, tid = threadIdx.x;
    const float* W; float b;
    if (o < 64)       { W = Wo_pol + (size_t)o * DK;        b = bo_pol[o]; }
    else if (o < 128) { W = Wd_pol + (size_t)(o - 64) * DK; b = bd_pol[o - 64]; }
    else              { W = Wv;                              b = bv[0]; }
    float4 h = ((const float4*)ol)[tid];
    float4 w = ((const float4*)W)[tid];
    float s = fmaxf(h.x, 0.f) * w.x + fmaxf(h.y, 0.f) * w.y
            + fmaxf(h.z, 0.f) * w.z + fmaxf(h.w, 0.f) * w.w;
    #pragma unroll
    for (int off = 32; off; off >>= 1) s += __shfl_down(s, off, 64);
    int wave = tid >> 6, lane = tid & 63;
    if (lane == 0) red[wave] = s;
    __syncthreads();
    if (tid == 0) out[o] = red[0] + red[1] + red[2] + red[3] + b;
}

// =====================================================================
extern "C" void kernel_launch(void* const* d_in, const int* in_sizes, int n_in,
                              void* d_out, int out_size, void* d_ws, size_t ws_size,
                              hipStream_t stream) {
    const int*   obs    = (const int*)  d_in[0];
    const float* o_emb  = (const float*)d_in[1];
    const float* d_emb  = (const float*)d_in[2];
    const float* WQ     = (const float*)d_in[3];
    const float* WK     = (const float*)d_in[4];
    const float* WV     = (const float*)d_in[5];
    const float* WO     = (const float*)d_in[6];
    const float* Wo_pol = (const float*)d_in[7];
    const float* bo_pol = (const float*)d_in[8];
    const float* Wd_pol = (const float*)d_in[9];
    const float* bd_pol = (const float*)d_in[10];
    const float* Wv     = (const float*)d_in[11];
    const float* bv     = (const float*)d_in[12];
    float* out = (float*)d_out;

    char* ws = (char*)d_ws;
    unsigned char* idxb = (unsigned char*)(ws + IDX_OFF);
    float* freqt = (float*)(ws + FRQ_OFF);
    float* kq    = (float*)(ws + KQ_OFF);
    float* s     = (float*)(ws + S_OFF);
    float* qp    = (float*)(ws + QP_OFF);
    float* axpe  = (float*)(ws + AXPE_OFF);
    float* wgt   = (float*)(ws + W_OFF);
    float* ctx   = (float*)(ws + CTX_OFF);
    float* ol    = (float*)(ws + OL_OFF);

    setup_k<<<257, 256, 0, stream>>>(obs, idxb, freqt, qp);
    q_k<<<256, 256, 0, stream>>>(obs, o_emb, d_emb, WQ, qp);
    kq_k<<<1024, 256, 0, stream>>>(WK, qp, kq);
    scores_k<<<256, 256, 0, stream>>>(kq, o_emb, d_emb, freqt, idxb, s);
    att_post_k<<<256, 256, 0, stream>>>(s, freqt, idxb, wgt, axpe);
    ctxv_k<<<128, 256, 0, stream>>>(wgt, axpe, o_emb, d_emb, WV, ctx);
    olast_k<<<64, 256, 0, stream>>>(ctx, WO, ol);
    heads_k<<<129, 256, 0, stream>>>(ol, Wo_pol, bo_pol, Wd_pol, bd_pol, Wv, bv, out);
}